// Round 9
// baseline (845.170 us; speedup 1.0000x reference)
//
#include <hip/hip_runtime.h>
#include <hip/hip_bf16.h>
#include <float.h>

#define NN 50000
#define EE 800000
#define GG 50
#define HH 4
#define DD 64
#define HD 256
#define NODE_IN 26
#define NEG_SLOPE 0.2f

typedef __attribute__((ext_vector_type(8))) short short8v;   // 8 bf16 = 4 VGPR
typedef __attribute__((ext_vector_type(4))) float floatx4;   // MFMA C/D

static __device__ __forceinline__ ushort f2bf(float f) {
    __hip_bfloat16 b = __float2bfloat16(f);
    return *(ushort*)&b;
}

static __device__ __forceinline__ float lrelu(float e) {
    return (e >= 0.f) ? e : NEG_SLOPE * e;
}

// ---------------------------------------------------------------------------
// embed -> bf16 padded: hbf[n][j], j in [0,32): W_emb | node_s | 0-pad
// ---------------------------------------------------------------------------
__global__ void embed_bf16_kernel(const int* __restrict__ seq,
                                  const float* __restrict__ node_s,
                                  const float* __restrict__ W_emb,
                                  ushort* __restrict__ hbf) {
    int idx = blockIdx.x * blockDim.x + threadIdx.x;
    if (idx >= NN * 32) return;
    int n = idx >> 5;
    int j = idx & 31;
    float v = 0.f;
    if (j < 20)      v = W_emb[seq[n] * 20 + j];
    else if (j < 26) v = node_s[n * 6 + (j - 20)];
    hbf[idx] = f2bf(v);
}

// ---------------------------------------------------------------------------
// weight transpose+convert: W fp32 [K,N] -> Wt bf16 [N,Kp] (zero-pad k>=K)
// ---------------------------------------------------------------------------
__global__ void wtrans_kernel(const float* __restrict__ W,
                              ushort* __restrict__ Wt,
                              int K, int N, int Kp) {
    int idx = blockIdx.x * blockDim.x + threadIdx.x;
    if (idx >= N * Kp) return;
    int n = idx / Kp;
    int k = idx - n * Kp;
    float v = (k < K) ? W[(size_t)k * N + n] : 0.f;
    Wt[idx] = f2bf(v);
}

// ---------------------------------------------------------------------------
// MFMA bf16 GEMM: C[M,N] = A[M,Kp] @ Bt[N,Kp]^T  (+bias, optional relu)
// block: 256 thr = 4 waves; tile 128(M) x 64(N); K-step 32.
// ---------------------------------------------------------------------------
__global__ __launch_bounds__(256) void gemm_mfma_kernel(
    const ushort* __restrict__ A, const ushort* __restrict__ Bt,
    float* __restrict__ C, const float* __restrict__ bias,
    int M, int N, int Kp, int relu_out) {
    __shared__ ushort As[128][40];
    __shared__ ushort Bs[64][40];

    int tid  = threadIdx.x;
    int wave = tid >> 6;
    int lane = tid & 63;
    int bm = blockIdx.y * 128;
    int bn = blockIdx.x * 64;

    floatx4 acc[2][4];
    #pragma unroll
    for (int i = 0; i < 2; ++i)
        #pragma unroll
        for (int j = 0; j < 4; ++j)
            acc[i][j] = (floatx4){0.f, 0.f, 0.f, 0.f};

    const int lr = lane & 15;          // row/col within 16-subtile
    const int lk = (lane >> 4) * 8;    // k-offset of this lane's 8 elements
    const int lq = lane >> 4;          // C row group

    for (int k0 = 0; k0 < Kp; k0 += 32) {
        #pragma unroll
        for (int p = 0; p < 2; ++p) {
            int idx = p * 256 + tid;
            int r = idx >> 2, kk = (idx & 3) * 8;
            int gr = bm + r;
            short8v v = {};
            if (gr < M) v = *(const short8v*)(A + (size_t)gr * Kp + k0 + kk);
            *(short8v*)(&As[r][kk]) = v;
        }
        {
            int c = tid >> 2, kk = (tid & 3) * 8;
            short8v v = *(const short8v*)(Bt + (size_t)(bn + c) * Kp + k0 + kk);
            *(short8v*)(&Bs[c][kk]) = v;
        }
        __syncthreads();

        short8v bfrag[4];
        #pragma unroll
        for (int cs = 0; cs < 4; ++cs)
            bfrag[cs] = *(const short8v*)(&Bs[cs * 16 + lr][lk]);
        #pragma unroll
        for (int rs = 0; rs < 2; ++rs) {
            short8v afrag = *(const short8v*)(&As[wave * 32 + rs * 16 + lr][lk]);
            #pragma unroll
            for (int cs = 0; cs < 4; ++cs)
                acc[rs][cs] = __builtin_amdgcn_mfma_f32_16x16x32_bf16(
                    afrag, bfrag[cs], acc[rs][cs], 0, 0, 0);
        }
        __syncthreads();
    }

    // epilogue: C/D layout col=lane&15, row=(lane>>4)*4+j  [m89/m91]
    #pragma unroll
    for (int rs = 0; rs < 2; ++rs)
        #pragma unroll
        for (int cs = 0; cs < 4; ++cs)
            #pragma unroll
            for (int j = 0; j < 4; ++j) {
                int row = bm + wave * 32 + rs * 16 + lq * 4 + j;
                int col = bn + cs * 16 + lr;
                if (row < M) {
                    float v = acc[rs][cs][j];
                    if (bias) v += bias[col];
                    if (relu_out) v = fmaxf(v, 0.f);
                    C[(size_t)row * N + col] = v;
                }
            }
}

// ---------------------------------------------------------------------------
// scores: el[n,h] = sum_d ft[n,h,d]*al[h,d]; er likewise. One wave per node.
// ---------------------------------------------------------------------------
__global__ __launch_bounds__(256) void scores_kernel(
    const float* __restrict__ ft, const float* __restrict__ al,
    const float* __restrict__ ar, float* __restrict__ el,
    float* __restrict__ er) {
    int wv = (blockIdx.x * blockDim.x + threadIdx.x) >> 6;
    int lane = threadIdx.x & 63;
    if (wv >= NN) return;
    float4 r = ((const float4*)(ft + (size_t)wv * HD))[lane];
    float4 a = ((const float4*)al)[lane];
    float4 b = ((const float4*)ar)[lane];
    float sl = r.x * a.x + r.y * a.y + r.z * a.z + r.w * a.w;
    float sr = r.x * b.x + r.y * b.y + r.z * b.z + r.w * b.w;
    #pragma unroll
    for (int off = 1; off < 16; off <<= 1) {
        sl += __shfl_xor(sl, off);
        sr += __shfl_xor(sr, off);
    }
    if ((lane & 15) == 0) {
        int h = lane >> 4;
        el[wv * HH + h] = sl;
        er[wv * HH + h] = sr;
    }
}

// ---------------------------------------------------------------------------
// CSR build: histogram over dst -> scan -> scatter src per slot
// ---------------------------------------------------------------------------
__global__ void hist_kernel(const int* __restrict__ dst, int* __restrict__ cnt) {
    for (int i = blockIdx.x * blockDim.x + threadIdx.x; i < EE;
         i += gridDim.x * blockDim.x)
        atomicAdd(&cnt[dst[i]], 1);
}

__global__ __launch_bounds__(1024) void scan_kernel(
    const int* __restrict__ cnt, int* __restrict__ rowptr) {
    __shared__ int part[1024];
    int t = threadIdx.x;
    const int per = (NN + 1023) / 1024;   // 49
    int start = t * per;
    int end = start + per; if (end > NN) end = NN;
    int s = 0;
    for (int i = start; i < end; ++i) s += cnt[i];
    part[t] = s;
    __syncthreads();
    for (int off = 1; off < 1024; off <<= 1) {
        int v = (t >= off) ? part[t - off] : 0;
        __syncthreads();
        part[t] += v;
        __syncthreads();
    }
    int run = (t == 0) ? 0 : part[t - 1];
    for (int i = start; i < end; ++i) { rowptr[i] = run; run += cnt[i]; }
    if (t == 1023) rowptr[NN] = part[1023];
}

__global__ void scatter_kernel(const int* __restrict__ src,
                               const int* __restrict__ dst,
                               const int* __restrict__ rowptr,
                               int* __restrict__ fill,
                               int* __restrict__ colsrc) {
    for (int i = blockIdx.x * blockDim.x + threadIdx.x; i < EE;
         i += gridDim.x * blockDim.x) {
        int d = dst[i];
        int pos = atomicAdd(&fill[d], 1);
        colsrc[rowptr[d] + pos] = src[i];
    }
}

// ---------------------------------------------------------------------------
// aggregate: per-dst-node edge softmax + message aggregation. One wave/node.
//
// R9: latency-oriented restructure.
//  - lane layout: head h = lane>>4, dims (lane&15)*4..+3  -> ONE float4
//    gather per lane per edge (was 4 dword gathers).
//  - per-64-edge chunk: lane-parallel p=exp(lrelu(el+er)) once; stage
//    (src, p0..p3) in per-wave LDS; serial loop does 2 broadcast LDS reads
//    per edge (uniform addr -> conflict-free) instead of 5 shfl + selects.
//  - unroll 4 -> 4 independent float4 gathers in flight.
// ---------------------------------------------------------------------------
__global__ __launch_bounds__(256) void aggregate_kernel(
    const float* __restrict__ ft, const float* __restrict__ el,
    const float* __restrict__ er, const int* __restrict__ rowptr,
    const int* __restrict__ colsrc, const float* __restrict__ bias,
    ushort* __restrict__ out, int relu_out) {
    __shared__ float4 plds[4][64];
    __shared__ int    slds[4][64];

    int v = (blockIdx.x * blockDim.x + threadIdx.x) >> 6;
    int lane = threadIdx.x & 63;
    int w = threadIdx.x >> 6;
    if (v >= NN) return;
    int base = rowptr[v];
    int deg = rowptr[v + 1] - base;

    const int h = lane >> 4;           // this lane's head
    float4 er4 = ((const float4*)er)[v];

    float z0 = 0.f, z1 = 0.f, z2 = 0.f, z3 = 0.f;
    float4 acc = {0.f, 0.f, 0.f, 0.f};
    const float* pf = (const float*)plds[w];

    for (int c = 0; c < deg; c += 64) {
        int clen = min(64, deg - c);
        if (lane < clen) {
            int s_j = colsrc[base + c + lane];
            float4 el4 = ((const float4*)el)[s_j];
            float p0 = expf(lrelu(el4.x + er4.x));
            float p1 = expf(lrelu(el4.y + er4.y));
            float p2 = expf(lrelu(el4.z + er4.z));
            float p3 = expf(lrelu(el4.w + er4.w));
            z0 += p0; z1 += p1; z2 += p2; z3 += p3;
            slds[w][lane] = s_j;
            plds[w][lane] = (float4){p0, p1, p2, p3};
        }
        // wave-internal LDS ordering; no __syncthreads needed
        #pragma unroll 4
        for (int jj = 0; jj < clen; ++jj) {
            int   s = slds[w][jj];                 // uniform broadcast
            float q = pf[jj * 4 + h];              // 4 distinct banks
            float4 f = ((const float4*)(ft + (size_t)s * HD))[lane];
            acc.x = fmaf(q, f.x, acc.x);
            acc.y = fmaf(q, f.y, acc.y);
            acc.z = fmaf(q, f.z, acc.z);
            acc.w = fmaf(q, f.w, acc.w);
        }
    }

    // reduce lane-partial z across the wave, then pick own head's z
    #pragma unroll
    for (int off = 32; off; off >>= 1) {
        z0 += __shfl_xor(z0, off);
        z1 += __shfl_xor(z1, off);
        z2 += __shfl_xor(z2, off);
        z3 += __shfl_xor(z3, off);
    }
    float zh = (h < 2) ? ((h == 0) ? z0 : z1) : ((h == 2) ? z2 : z3);
    float zi = 1.f / zh;

    float4 b4 = ((const float4*)bias)[lane];
    float o0 = acc.x * zi + b4.x;
    float o1 = acc.y * zi + b4.y;
    float o2 = acc.z * zi + b4.z;
    float o3 = acc.w * zi + b4.w;
    if (relu_out) {
        o0 = fmaxf(o0, 0.f); o1 = fmaxf(o1, 0.f);
        o2 = fmaxf(o2, 0.f); o3 = fmaxf(o3, 0.f);
    }
    ushort4 st = {f2bf(o0), f2bf(o1), f2bf(o2), f2bf(o3)};
    *(ushort4*)(out + (size_t)v * HD + lane * 4) = st;
}

// ---------------------------------------------------------------------------
// final: out[n] = hidden[n,:512] . Wd2 + bd2 + 0.5  (no atomics)
// ---------------------------------------------------------------------------
__global__ __launch_bounds__(256) void final_kernel(
    const float* __restrict__ hidden, const float* __restrict__ Wd2,
    const float* __restrict__ bd2, float* __restrict__ out) {
    int n = (blockIdx.x * blockDim.x + threadIdx.x) >> 6;
    int lane = threadIdx.x & 63;
    if (n >= NN) return;
    const float4* hr = (const float4*)(hidden + (size_t)n * 512);
    const float4* w  = (const float4*)Wd2;
    float4 a0 = hr[lane];
    float4 a1 = hr[lane + 64];
    float4 w0 = w[lane];
    float4 w1 = w[lane + 64];
    float s = a0.x * w0.x + a0.y * w0.y + a0.z * w0.z + a0.w * w0.w
            + a1.x * w1.x + a1.y * w1.y + a1.z * w1.z + a1.w * w1.w;
    #pragma unroll
    for (int off = 32; off; off >>= 1) s += __shfl_xor(s, off);
    if (lane == 0) out[n] = s + bd2[0] + 0.5f;
}

// ---------------------------------------------------------------------------
// pool: one block per graph; masked block reduction over all nodes (no atomics)
// ---------------------------------------------------------------------------
__global__ __launch_bounds__(256) void pool_kernel(
    const float* __restrict__ out, const int* __restrict__ graph_id,
    float* __restrict__ gout) {
    int g = blockIdx.x;
    int t = threadIdx.x;
    float s = 0.f;
    float c = 0.f;
    for (int n = t; n < NN; n += 256) {
        if (graph_id[n] == g) { s += out[n]; c += 1.f; }
    }
    __shared__ float ss[256], cc[256];
    ss[t] = s; cc[t] = c;
    __syncthreads();
    for (int off = 128; off; off >>= 1) {
        if (t < off) { ss[t] += ss[t + off]; cc[t] += cc[t + off]; }
        __syncthreads();
    }
    if (t == 0) gout[g] = ss[0] / cc[0];
}

// ---------------------------------------------------------------------------
// launch
// ---------------------------------------------------------------------------
static inline size_t align_up(size_t x, size_t a) { return (x + a - 1) & ~(a - 1); }

extern "C" void kernel_launch(void* const* d_in, const int* in_sizes, int n_in,
                              void* d_out, int out_size, void* d_ws, size_t ws_size,
                              hipStream_t stream) {
    const int*   seq    = (const int*)d_in[0];
    const float* node_s = (const float*)d_in[1];
    const int*   src    = (const int*)d_in[2];
    const int*   dst    = (const int*)d_in[3];
    const int*   graph_id = (const int*)d_in[4];
    const float* W_emb  = (const float*)d_in[5];
    const float* W0     = (const float*)d_in[6];
    const float* al0    = (const float*)d_in[7];
    const float* ar0    = (const float*)d_in[8];
    const float* b0     = (const float*)d_in[9];
    const float* W1     = (const float*)d_in[10];
    const float* al1    = (const float*)d_in[11];
    const float* ar1    = (const float*)d_in[12];
    const float* b1     = (const float*)d_in[13];
    const float* W2     = (const float*)d_in[14];
    const float* al2    = (const float*)d_in[15];
    const float* ar2    = (const float*)d_in[16];
    const float* b2     = (const float*)d_in[17];
    const float* Wd1    = (const float*)d_in[18];
    const float* bd1    = (const float*)d_in[19];
    const float* Wd2    = (const float*)d_in[20];
    const float* bd2    = (const float*)d_in[21];

    float* out_nodes  = (float*)d_out;          // [N]
    float* out_graphs = (float*)d_out + NN;     // [G]

    // workspace carve-up
    char* p = (char*)d_ws;
    size_t off = 0;
    auto alloc = [&](size_t bytes) {
        void* r = p + off;
        off = align_up(off + bytes, 256);
        return r;
    };
    float*  ftbuf = (float*)alloc((size_t)NN * 512 * 4);   // ft / hidden (fp32)
    ushort* hbf0  = (ushort*)alloc((size_t)NN * 32 * 2);   // embed output bf16 [N,32]
    ushort* hbuf  = (ushort*)alloc((size_t)NN * HD * 2);   // h between layers, bf16
    float*  el    = (float*)alloc((size_t)NN * HH * 4);
    float*  er    = (float*)alloc((size_t)NN * HH * 4);
    int*    rowptr= (int*)alloc((size_t)(NN + 1) * 4);
    int*    fill  = (int*)alloc((size_t)NN * 4);
    int*    colsrc= (int*)alloc((size_t)EE * 4);
    ushort* Wt0   = (ushort*)alloc((size_t)HD * 32 * 2);   // [256][32]
    ushort* Wt1   = (ushort*)alloc((size_t)HD * HD * 2);   // [256][256]
    ushort* Wt2   = (ushort*)alloc((size_t)HD * HD * 2);
    ushort* Wtd1  = (ushort*)alloc((size_t)512 * HD * 2);  // [512][256]
    (void)ws_size;

    // ---- CSR build (dst-grouped) ----
    hipMemsetAsync(fill, 0, (size_t)NN * 4, stream);
    hist_kernel<<<1024, 256, 0, stream>>>(dst, fill);
    scan_kernel<<<1, 1024, 0, stream>>>(fill, rowptr);
    hipMemsetAsync(fill, 0, (size_t)NN * 4, stream);
    scatter_kernel<<<1024, 256, 0, stream>>>(src, dst, rowptr, fill, colsrc);

    // ---- weight transposes (bf16) ----
    wtrans_kernel<<<(HD * 32 + 255) / 256, 256, 0, stream>>>(W0, Wt0, NODE_IN, HD, 32);
    wtrans_kernel<<<(HD * HD + 255) / 256, 256, 0, stream>>>(W1, Wt1, HD, HD, HD);
    wtrans_kernel<<<(HD * HD + 255) / 256, 256, 0, stream>>>(W2, Wt2, HD, HD, HD);
    wtrans_kernel<<<(512 * HD + 255) / 256, 256, 0, stream>>>(Wd1, Wtd1, HD, 512, HD);

    // ---- embedding (bf16, padded to K=32) ----
    embed_bf16_kernel<<<(NN * 32 + 255) / 256, 256, 0, stream>>>(seq, node_s, W_emb, hbf0);

    const int nodeWaves = (NN * 64 + 255) / 256;  // blocks of 4 waves
    dim3 gemm256(256 / 64, (NN + 127) / 128);
    dim3 gemm512(512 / 64, (NN + 127) / 128);

    // ---- layer 0 ----
    gemm_mfma_kernel<<<gemm256, 256, 0, stream>>>(hbf0, Wt0, ftbuf, nullptr, NN, HD, 32, 0);
    scores_kernel<<<nodeWaves, 256, 0, stream>>>(ftbuf, al0, ar0, el, er);
    aggregate_kernel<<<nodeWaves, 256, 0, stream>>>(ftbuf, el, er, rowptr, colsrc, b0, hbuf, 0);

    // ---- layer 1 ----
    gemm_mfma_kernel<<<gemm256, 256, 0, stream>>>(hbuf, Wt1, ftbuf, nullptr, NN, HD, HD, 0);
    scores_kernel<<<nodeWaves, 256, 0, stream>>>(ftbuf, al1, ar1, el, er);
    aggregate_kernel<<<nodeWaves, 256, 0, stream>>>(ftbuf, el, er, rowptr, colsrc, b1, hbuf, 0);

    // ---- layer 2 (relu fused into aggregate epilogue) ----
    gemm_mfma_kernel<<<gemm256, 256, 0, stream>>>(hbuf, Wt2, ftbuf, nullptr, NN, HD, HD, 0);
    scores_kernel<<<nodeWaves, 256, 0, stream>>>(ftbuf, al2, ar2, el, er);
    aggregate_kernel<<<nodeWaves, 256, 0, stream>>>(ftbuf, el, er, rowptr, colsrc, b2, hbuf, 1);

    // ---- dense head: hidden = relu(h @ Wd1 + bd1)  (fp32 out) ----
    gemm_mfma_kernel<<<gemm512, 256, 0, stream>>>(hbuf, Wtd1, ftbuf, bd1, NN, 512, HD, 1);
    final_kernel<<<nodeWaves, 256, 0, stream>>>(ftbuf, Wd2, bd2, out_nodes);
    pool_kernel<<<GG, 256, 0, stream>>>(out_nodes, graph_id, out_graphs);
}

// Round 12
// 653.436 us; speedup vs baseline: 1.2934x; 1.2934x over previous
//
#include <hip/hip_runtime.h>
#include <hip/hip_bf16.h>
#include <float.h>

#define NN 50000
#define EE 800000
#define GG 50
#define HH 4
#define DD 64
#define HD 256
#define NODE_IN 26
#define NEG_SLOPE 0.2f

typedef __attribute__((ext_vector_type(8))) short short8v;   // 8 bf16 = 4 VGPR
typedef __attribute__((ext_vector_type(4))) float floatx4;   // MFMA C/D

static __device__ __forceinline__ ushort f2bf(float f) {
    __hip_bfloat16 b = __float2bfloat16(f);
    return *(ushort*)&b;
}

static __device__ __forceinline__ float bf2f(ushort u) {
    return __uint_as_float(((unsigned)u) << 16);
}

static __device__ __forceinline__ float lrelu(float e) {
    return (e >= 0.f) ? e : NEG_SLOPE * e;
}

// ---------------------------------------------------------------------------
// embed -> bf16 padded: hbf[n][j], j in [0,32): W_emb | node_s | 0-pad
// ---------------------------------------------------------------------------
__global__ void embed_bf16_kernel(const int* __restrict__ seq,
                                  const float* __restrict__ node_s,
                                  const float* __restrict__ W_emb,
                                  ushort* __restrict__ hbf) {
    int idx = blockIdx.x * blockDim.x + threadIdx.x;
    if (idx >= NN * 32) return;
    int n = idx >> 5;
    int j = idx & 31;
    float v = 0.f;
    if (j < 20)      v = W_emb[seq[n] * 20 + j];
    else if (j < 26) v = node_s[n * 6 + (j - 20)];
    hbf[idx] = f2bf(v);
}

// ---------------------------------------------------------------------------
// weight transpose+convert: W fp32 [K,N] -> Wt bf16 [N,Kp] (zero-pad k>=K)
// ---------------------------------------------------------------------------
__global__ void wtrans_kernel(const float* __restrict__ W,
                              ushort* __restrict__ Wt,
                              int K, int N, int Kp) {
    int idx = blockIdx.x * blockDim.x + threadIdx.x;
    if (idx >= N * Kp) return;
    int n = idx / Kp;
    int k = idx - n * Kp;
    float v = (k < K) ? W[(size_t)k * N + n] : 0.f;
    Wt[idx] = f2bf(v);
}

// ---------------------------------------------------------------------------
// MFMA bf16 GEMM: C = A[M,Kp] @ Bt[N,Kp]^T   (+bias, optional relu)
// Output: bf16 (Cbf) or fp32 (Cf).
// Fused GAT scores (when al!=nullptr): each 64-col block == one head, so the
// block owns the full head-dot: el[row,h]=sum_d ft*al (from fp32 acc,
// pre-bias/pre-relu, matching reference), 16-lane shfl reduce, lr==0 stores.
// block: 256 thr = 4 waves; tile 128(M) x 64(N); K-step 32.
// ---------------------------------------------------------------------------
__global__ __launch_bounds__(256) void gemm_mfma_kernel(
    const ushort* __restrict__ A, const ushort* __restrict__ Bt,
    ushort* __restrict__ Cbf, float* __restrict__ Cf,
    const float* __restrict__ bias,
    const float* __restrict__ al, const float* __restrict__ ar,
    float* __restrict__ el, float* __restrict__ er,
    int M, int N, int Kp, int relu_out) {
    __shared__ ushort As[128][40];
    __shared__ ushort Bs[64][40];

    int tid  = threadIdx.x;
    int wave = tid >> 6;
    int lane = tid & 63;
    int bm = blockIdx.y * 128;
    int bn = blockIdx.x * 64;

    floatx4 acc[2][4];
    #pragma unroll
    for (int i = 0; i < 2; ++i)
        #pragma unroll
        for (int j = 0; j < 4; ++j)
            acc[i][j] = (floatx4){0.f, 0.f, 0.f, 0.f};

    const int lr = lane & 15;          // row/col within 16-subtile
    const int lk = (lane >> 4) * 8;    // k-offset of this lane's 8 elements
    const int lq = lane >> 4;          // C row group

    for (int k0 = 0; k0 < Kp; k0 += 32) {
        #pragma unroll
        for (int p = 0; p < 2; ++p) {
            int idx = p * 256 + tid;
            int r = idx >> 2, kk = (idx & 3) * 8;
            int gr = bm + r;
            short8v v = {};
            if (gr < M) v = *(const short8v*)(A + (size_t)gr * Kp + k0 + kk);
            *(short8v*)(&As[r][kk]) = v;
        }
        {
            int c = tid >> 2, kk = (tid & 3) * 8;
            short8v v = *(const short8v*)(Bt + (size_t)(bn + c) * Kp + k0 + kk);
            *(short8v*)(&Bs[c][kk]) = v;
        }
        __syncthreads();

        short8v bfrag[4];
        #pragma unroll
        for (int cs = 0; cs < 4; ++cs)
            bfrag[cs] = *(const short8v*)(&Bs[cs * 16 + lr][lk]);
        #pragma unroll
        for (int rs = 0; rs < 2; ++rs) {
            short8v afrag = *(const short8v*)(&As[wave * 32 + rs * 16 + lr][lk]);
            #pragma unroll
            for (int cs = 0; cs < 4; ++cs)
                acc[rs][cs] = __builtin_amdgcn_mfma_f32_16x16x32_bf16(
                    afrag, bfrag[cs], acc[rs][cs], 0, 0, 0);
        }
        __syncthreads();
    }

    // fused-score weight slices for this head block (bn/64 == head)
    const int h_blk = bn >> 6;
    float alv[4], arv[4];
    if (al) {
        #pragma unroll
        for (int cs = 0; cs < 4; ++cs) {
            alv[cs] = al[h_blk * DD + cs * 16 + lr];
            arv[cs] = ar[h_blk * DD + cs * 16 + lr];
        }
    }

    // epilogue: C/D layout col=lane&15, row=(lane>>4)*4+j  [m89/m91]
    #pragma unroll
    for (int rs = 0; rs < 2; ++rs)
        #pragma unroll
        for (int j = 0; j < 4; ++j) {
            int row = bm + wave * 32 + rs * 16 + lq * 4 + j;
            if (row >= M) continue;
            float sl = 0.f, sr = 0.f;
            #pragma unroll
            for (int cs = 0; cs < 4; ++cs) {
                float raw = acc[rs][cs][j];
                float v = raw;
                int col = bn + cs * 16 + lr;
                if (bias) v += bias[col];
                if (relu_out) v = fmaxf(v, 0.f);
                if (Cbf) Cbf[(size_t)row * N + col] = f2bf(v);
                else     Cf [(size_t)row * N + col] = v;
                if (al) {
                    sl = fmaf(raw, alv[cs], sl);
                    sr = fmaf(raw, arv[cs], sr);
                }
            }
            if (al) {
                #pragma unroll
                for (int off = 1; off < 16; off <<= 1) {
                    sl += __shfl_xor(sl, off);
                    sr += __shfl_xor(sr, off);
                }
                if (lr == 0) {
                    el[row * HH + h_blk] = sl;
                    er[row * HH + h_blk] = sr;
                }
            }
        }
}

// ---------------------------------------------------------------------------
// CSR build: histogram over dst -> scan -> scatter src per slot
// ---------------------------------------------------------------------------
__global__ void hist_kernel(const int* __restrict__ dst, int* __restrict__ cnt) {
    for (int i = blockIdx.x * blockDim.x + threadIdx.x; i < EE;
         i += gridDim.x * blockDim.x)
        atomicAdd(&cnt[dst[i]], 1);
}

__global__ __launch_bounds__(1024) void scan_kernel(
    const int* __restrict__ cnt, int* __restrict__ rowptr) {
    __shared__ int part[1024];
    int t = threadIdx.x;
    const int per = (NN + 1023) / 1024;   // 49
    int start = t * per;
    int end = start + per; if (end > NN) end = NN;
    int s = 0;
    for (int i = start; i < end; ++i) s += cnt[i];
    part[t] = s;
    __syncthreads();
    for (int off = 1; off < 1024; off <<= 1) {
        int v = (t >= off) ? part[t - off] : 0;
        __syncthreads();
        part[t] += v;
        __syncthreads();
    }
    int run = (t == 0) ? 0 : part[t - 1];
    for (int i = start; i < end; ++i) { rowptr[i] = run; run += cnt[i]; }
    if (t == 1023) rowptr[NN] = part[1023];
}

__global__ void scatter_kernel(const int* __restrict__ src,
                               const int* __restrict__ dst,
                               const int* __restrict__ rowptr,
                               int* __restrict__ fill,
                               int* __restrict__ colsrc) {
    for (int i = blockIdx.x * blockDim.x + threadIdx.x; i < EE;
         i += gridDim.x * blockDim.x) {
        int d = dst[i];
        int pos = atomicAdd(&fill[d], 1);
        colsrc[rowptr[d] + pos] = src[i];
    }
}

// ---------------------------------------------------------------------------
// aggregate: per-dst-node edge softmax + message aggregation. One wave/node.
// ft is bf16: one ushort4 (8B) gather per lane per edge -> 512B/wave per edge
// (was 1KB fp32). Softmax exp computed once lane-parallel; (src,p) staged in
// per-wave LDS; serial loop: 2 broadcast LDS reads + 1 bf16x4 gather.
// ---------------------------------------------------------------------------
__global__ __launch_bounds__(256) void aggregate_kernel(
    const ushort* __restrict__ ft, const float* __restrict__ el,
    const float* __restrict__ er, const int* __restrict__ rowptr,
    const int* __restrict__ colsrc, const float* __restrict__ bias,
    ushort* __restrict__ out, int relu_out) {
    __shared__ float4 plds[4][64];
    __shared__ int    slds[4][64];

    int v = (blockIdx.x * blockDim.x + threadIdx.x) >> 6;
    int lane = threadIdx.x & 63;
    int w = threadIdx.x >> 6;
    if (v >= NN) return;
    int base = rowptr[v];
    int deg = rowptr[v + 1] - base;

    const int h = lane >> 4;           // this lane's head
    float4 er4 = ((const float4*)er)[v];

    float z0 = 0.f, z1 = 0.f, z2 = 0.f, z3 = 0.f;
    float4 acc = {0.f, 0.f, 0.f, 0.f};
    const float* pf = (const float*)plds[w];

    for (int c = 0; c < deg; c += 64) {
        int clen = min(64, deg - c);
        if (lane < clen) {
            int s_j = colsrc[base + c + lane];
            float4 el4 = ((const float4*)el)[s_j];
            float p0 = expf(lrelu(el4.x + er4.x));
            float p1 = expf(lrelu(el4.y + er4.y));
            float p2 = expf(lrelu(el4.z + er4.z));
            float p3 = expf(lrelu(el4.w + er4.w));
            z0 += p0; z1 += p1; z2 += p2; z3 += p3;
            slds[w][lane] = s_j;
            plds[w][lane] = (float4){p0, p1, p2, p3};
        }
        // wave-internal LDS ordering; no __syncthreads needed
        #pragma unroll 4
        for (int jj = 0; jj < clen; ++jj) {
            int   s = slds[w][jj];                 // uniform broadcast
            float q = pf[jj * 4 + h];
            ushort4 f4 = ((const ushort4*)(ft + (size_t)s * HD))[lane];
            acc.x = fmaf(q, bf2f(f4.x), acc.x);
            acc.y = fmaf(q, bf2f(f4.y), acc.y);
            acc.z = fmaf(q, bf2f(f4.z), acc.z);
            acc.w = fmaf(q, bf2f(f4.w), acc.w);
        }
    }

    // reduce lane-partial z across the wave, then pick own head's z
    #pragma unroll
    for (int off = 32; off; off >>= 1) {
        z0 += __shfl_xor(z0, off);
        z1 += __shfl_xor(z1, off);
        z2 += __shfl_xor(z2, off);
        z3 += __shfl_xor(z3, off);
    }
    float zh = (h < 2) ? ((h == 0) ? z0 : z1) : ((h == 2) ? z2 : z3);
    float zi = 1.f / zh;

    float4 b4 = ((const float4*)bias)[lane];
    float o0 = acc.x * zi + b4.x;
    float o1 = acc.y * zi + b4.y;
    float o2 = acc.z * zi + b4.z;
    float o3 = acc.w * zi + b4.w;
    if (relu_out) {
        o0 = fmaxf(o0, 0.f); o1 = fmaxf(o1, 0.f);
        o2 = fmaxf(o2, 0.f); o3 = fmaxf(o3, 0.f);
    }
    ushort4 st = {f2bf(o0), f2bf(o1), f2bf(o2), f2bf(o3)};
    *(ushort4*)(out + (size_t)v * HD + lane * 4) = st;
}

// ---------------------------------------------------------------------------
// final: out[n] = hidden[n,:512] . Wd2 + bd2 + 0.5  (no atomics)
// ---------------------------------------------------------------------------
__global__ __launch_bounds__(256) void final_kernel(
    const float* __restrict__ hidden, const float* __restrict__ Wd2,
    const float* __restrict__ bd2, float* __restrict__ out) {
    int n = (blockIdx.x * blockDim.x + threadIdx.x) >> 6;
    int lane = threadIdx.x & 63;
    if (n >= NN) return;
    const float4* hr = (const float4*)(hidden + (size_t)n * 512);
    const float4* w  = (const float4*)Wd2;
    float4 a0 = hr[lane];
    float4 a1 = hr[lane + 64];
    float4 w0 = w[lane];
    float4 w1 = w[lane + 64];
    float s = a0.x * w0.x + a0.y * w0.y + a0.z * w0.z + a0.w * w0.w
            + a1.x * w1.x + a1.y * w1.y + a1.z * w1.z + a1.w * w1.w;
    #pragma unroll
    for (int off = 32; off; off >>= 1) s += __shfl_xor(s, off);
    if (lane == 0) out[n] = s + bd2[0] + 0.5f;
}

// ---------------------------------------------------------------------------
// pool: one block per graph; masked block reduction over all nodes (no atomics)
// ---------------------------------------------------------------------------
__global__ __launch_bounds__(256) void pool_kernel(
    const float* __restrict__ out, const int* __restrict__ graph_id,
    float* __restrict__ gout) {
    int g = blockIdx.x;
    int t = threadIdx.x;
    float s = 0.f;
    float c = 0.f;
    for (int n = t; n < NN; n += 256) {
        if (graph_id[n] == g) { s += out[n]; c += 1.f; }
    }
    __shared__ float ss[256], cc[256];
    ss[t] = s; cc[t] = c;
    __syncthreads();
    for (int off = 128; off; off >>= 1) {
        if (t < off) { ss[t] += ss[t + off]; cc[t] += cc[t + off]; }
        __syncthreads();
    }
    if (t == 0) gout[g] = ss[0] / cc[0];
}

// ---------------------------------------------------------------------------
// launch
// ---------------------------------------------------------------------------
static inline size_t align_up(size_t x, size_t a) { return (x + a - 1) & ~(a - 1); }

extern "C" void kernel_launch(void* const* d_in, const int* in_sizes, int n_in,
                              void* d_out, int out_size, void* d_ws, size_t ws_size,
                              hipStream_t stream) {
    const int*   seq    = (const int*)d_in[0];
    const float* node_s = (const float*)d_in[1];
    const int*   src    = (const int*)d_in[2];
    const int*   dst    = (const int*)d_in[3];
    const int*   graph_id = (const int*)d_in[4];
    const float* W_emb  = (const float*)d_in[5];
    const float* W0     = (const float*)d_in[6];
    const float* al0    = (const float*)d_in[7];
    const float* ar0    = (const float*)d_in[8];
    const float* b0     = (const float*)d_in[9];
    const float* W1     = (const float*)d_in[10];
    const float* al1    = (const float*)d_in[11];
    const float* ar1    = (const float*)d_in[12];
    const float* b1     = (const float*)d_in[13];
    const float* W2     = (const float*)d_in[14];
    const float* al2    = (const float*)d_in[15];
    const float* ar2    = (const float*)d_in[16];
    const float* b2     = (const float*)d_in[17];
    const float* Wd1    = (const float*)d_in[18];
    const float* bd1    = (const float*)d_in[19];
    const float* Wd2    = (const float*)d_in[20];
    const float* bd2    = (const float*)d_in[21];

    float* out_nodes  = (float*)d_out;          // [N]
    float* out_graphs = (float*)d_out + NN;     // [G]

    // workspace carve-up
    char* p = (char*)d_ws;
    size_t off = 0;
    auto alloc = [&](size_t bytes) {
        void* r = p + off;
        off = align_up(off + bytes, 256);
        return r;
    };
    ushort* ftbf  = (ushort*)alloc((size_t)NN * HD * 2);   // ft bf16 [N,256]
    float*  hidden= (float*)alloc((size_t)NN * 512 * 4);   // head GEMM out fp32
    ushort* hbf0  = (ushort*)alloc((size_t)NN * 32 * 2);   // embed output bf16 [N,32]
    ushort* hbuf  = (ushort*)alloc((size_t)NN * HD * 2);   // h between layers, bf16
    float*  el    = (float*)alloc((size_t)NN * HH * 4);
    float*  er    = (float*)alloc((size_t)NN * HH * 4);
    int*    rowptr= (int*)alloc((size_t)(NN + 1) * 4);
    int*    fill  = (int*)alloc((size_t)NN * 4);
    int*    colsrc= (int*)alloc((size_t)EE * 4);
    ushort* Wt0   = (ushort*)alloc((size_t)HD * 32 * 2);   // [256][32]
    ushort* Wt1   = (ushort*)alloc((size_t)HD * HD * 2);   // [256][256]
    ushort* Wt2   = (ushort*)alloc((size_t)HD * HD * 2);
    ushort* Wtd1  = (ushort*)alloc((size_t)512 * HD * 2);  // [512][256]
    (void)ws_size;

    // ---- CSR build (dst-grouped) ----
    hipMemsetAsync(fill, 0, (size_t)NN * 4, stream);
    hist_kernel<<<1024, 256, 0, stream>>>(dst, fill);
    scan_kernel<<<1, 1024, 0, stream>>>(fill, rowptr);
    hipMemsetAsync(fill, 0, (size_t)NN * 4, stream);
    scatter_kernel<<<1024, 256, 0, stream>>>(src, dst, rowptr, fill, colsrc);

    // ---- weight transposes (bf16) ----
    wtrans_kernel<<<(HD * 32 + 255) / 256, 256, 0, stream>>>(W0, Wt0, NODE_IN, HD, 32);
    wtrans_kernel<<<(HD * HD + 255) / 256, 256, 0, stream>>>(W1, Wt1, HD, HD, HD);
    wtrans_kernel<<<(HD * HD + 255) / 256, 256, 0, stream>>>(W2, Wt2, HD, HD, HD);
    wtrans_kernel<<<(512 * HD + 255) / 256, 256, 0, stream>>>(Wd1, Wtd1, HD, 512, HD);

    // ---- embedding (bf16, padded to K=32) ----
    embed_bf16_kernel<<<(NN * 32 + 255) / 256, 256, 0, stream>>>(seq, node_s, W_emb, hbf0);

    const int nodeWaves = (NN * 64 + 255) / 256;  // blocks of 4 waves
    dim3 gemm256(256 / 64, (NN + 127) / 128);
    dim3 gemm512(512 / 64, (NN + 127) / 128);

    // ---- layer 0 (scores fused into GEMM epilogue) ----
    gemm_mfma_kernel<<<gemm256, 256, 0, stream>>>(hbf0, Wt0, ftbf, nullptr, nullptr,
                                                  al0, ar0, el, er, NN, HD, 32, 0);
    aggregate_kernel<<<nodeWaves, 256, 0, stream>>>(ftbf, el, er, rowptr, colsrc, b0, hbuf, 0);

    // ---- layer 1 ----
    gemm_mfma_kernel<<<gemm256, 256, 0, stream>>>(hbuf, Wt1, ftbf, nullptr, nullptr,
                                                  al1, ar1, el, er, NN, HD, HD, 0);
    aggregate_kernel<<<nodeWaves, 256, 0, stream>>>(ftbf, el, er, rowptr, colsrc, b1, hbuf, 0);

    // ---- layer 2 (relu fused into aggregate epilogue) ----
    gemm_mfma_kernel<<<gemm256, 256, 0, stream>>>(hbuf, Wt2, ftbf, nullptr, nullptr,
                                                  al2, ar2, el, er, NN, HD, HD, 0);
    aggregate_kernel<<<nodeWaves, 256, 0, stream>>>(ftbf, el, er, rowptr, colsrc, b2, hbuf, 1);

    // ---- dense head: hidden = relu(h @ Wd1 + bd1)  (fp32 out, no scores) ----
    gemm_mfma_kernel<<<gemm512, 256, 0, stream>>>(hbuf, Wtd1, nullptr, hidden, bd1,
                                                  nullptr, nullptr, nullptr, nullptr,
                                                  NN, 512, HD, 1);
    final_kernel<<<nodeWaves, 256, 0, stream>>>(hidden, Wd2, bd2, out_nodes);
    pool_kernel<<<GG, 256, 0, stream>>>(out_nodes, graph_id, out_graphs);
}

// Round 15
// 636.986 us; speedup vs baseline: 1.3268x; 1.0258x over previous
//
#include <hip/hip_runtime.h>
#include <hip/hip_bf16.h>
#include <float.h>

#define NN 50000
#define EE 800000
#define GG 50
#define HH 4
#define DD 64
#define HD 256
#define NODE_IN 26
#define NEG_SLOPE 0.2f
#define SCAN_NB ((NN + 255) / 256)   // 196

typedef __attribute__((ext_vector_type(8))) short short8v;   // 8 bf16 = 4 VGPR
typedef __attribute__((ext_vector_type(4))) float floatx4;   // MFMA C/D

static __device__ __forceinline__ ushort f2bf(float f) {
    __hip_bfloat16 b = __float2bfloat16(f);
    return *(ushort*)&b;
}

static __device__ __forceinline__ float bf2f(ushort u) {
    return __uint_as_float(((unsigned)u) << 16);
}

static __device__ __forceinline__ float lrelu(float e) {
    return (e >= 0.f) ? e : NEG_SLOPE * e;
}

// ---------------------------------------------------------------------------
// embed -> bf16 padded: hbf[n][j], j in [0,32): W_emb | node_s | 0-pad
// ---------------------------------------------------------------------------
__global__ void embed_bf16_kernel(const int* __restrict__ seq,
                                  const float* __restrict__ node_s,
                                  const float* __restrict__ W_emb,
                                  ushort* __restrict__ hbf) {
    int idx = blockIdx.x * blockDim.x + threadIdx.x;
    if (idx >= NN * 32) return;
    int n = idx >> 5;
    int j = idx & 31;
    float v = 0.f;
    if (j < 20)      v = W_emb[seq[n] * 20 + j];
    else if (j < 26) v = node_s[n * 6 + (j - 20)];
    hbf[idx] = f2bf(v);
}

// ---------------------------------------------------------------------------
// weight transpose+convert: W fp32 [K,N] -> Wt bf16 [N,Kp] (zero-pad k>=K)
// ---------------------------------------------------------------------------
__global__ void wtrans_kernel(const float* __restrict__ W,
                              ushort* __restrict__ Wt,
                              int K, int N, int Kp) {
    int idx = blockIdx.x * blockDim.x + threadIdx.x;
    if (idx >= N * Kp) return;
    int n = idx / Kp;
    int k = idx - n * Kp;
    float v = (k < K) ? W[(size_t)k * N + n] : 0.f;
    Wt[idx] = f2bf(v);
}

// ---------------------------------------------------------------------------
// MFMA bf16 GEMM: C = A[M,Kp] @ Bt[N,Kp]^T   (+bias, optional relu)
// Output: bf16 (Cbf) or fp32 (Cf).
// Fused GAT scores (when al!=nullptr): each 64-col block == one head.
// block: 256 thr = 4 waves; tile 128(M) x 64(N); K-step 32.
// ---------------------------------------------------------------------------
__global__ __launch_bounds__(256) void gemm_mfma_kernel(
    const ushort* __restrict__ A, const ushort* __restrict__ Bt,
    ushort* __restrict__ Cbf, float* __restrict__ Cf,
    const float* __restrict__ bias,
    const float* __restrict__ al, const float* __restrict__ ar,
    float* __restrict__ el, float* __restrict__ er,
    int M, int N, int Kp, int relu_out) {
    __shared__ ushort As[128][40];
    __shared__ ushort Bs[64][40];

    int tid  = threadIdx.x;
    int wave = tid >> 6;
    int lane = tid & 63;
    int bm = blockIdx.y * 128;
    int bn = blockIdx.x * 64;

    floatx4 acc[2][4];
    #pragma unroll
    for (int i = 0; i < 2; ++i)
        #pragma unroll
        for (int j = 0; j < 4; ++j)
            acc[i][j] = (floatx4){0.f, 0.f, 0.f, 0.f};

    const int lr = lane & 15;          // row/col within 16-subtile
    const int lk = (lane >> 4) * 8;    // k-offset of this lane's 8 elements
    const int lq = lane >> 4;          // C row group

    for (int k0 = 0; k0 < Kp; k0 += 32) {
        #pragma unroll
        for (int p = 0; p < 2; ++p) {
            int idx = p * 256 + tid;
            int r = idx >> 2, kk = (idx & 3) * 8;
            int gr = bm + r;
            short8v v = {};
            if (gr < M) v = *(const short8v*)(A + (size_t)gr * Kp + k0 + kk);
            *(short8v*)(&As[r][kk]) = v;
        }
        {
            int c = tid >> 2, kk = (tid & 3) * 8;
            short8v v = *(const short8v*)(Bt + (size_t)(bn + c) * Kp + k0 + kk);
            *(short8v*)(&Bs[c][kk]) = v;
        }
        __syncthreads();

        short8v bfrag[4];
        #pragma unroll
        for (int cs = 0; cs < 4; ++cs)
            bfrag[cs] = *(const short8v*)(&Bs[cs * 16 + lr][lk]);
        #pragma unroll
        for (int rs = 0; rs < 2; ++rs) {
            short8v afrag = *(const short8v*)(&As[wave * 32 + rs * 16 + lr][lk]);
            #pragma unroll
            for (int cs = 0; cs < 4; ++cs)
                acc[rs][cs] = __builtin_amdgcn_mfma_f32_16x16x32_bf16(
                    afrag, bfrag[cs], acc[rs][cs], 0, 0, 0);
        }
        __syncthreads();
    }

    // fused-score weight slices for this head block (bn/64 == head)
    const int h_blk = bn >> 6;
    float alv[4], arv[4];
    if (al) {
        #pragma unroll
        for (int cs = 0; cs < 4; ++cs) {
            alv[cs] = al[h_blk * DD + cs * 16 + lr];
            arv[cs] = ar[h_blk * DD + cs * 16 + lr];
        }
    }

    // epilogue: C/D layout col=lane&15, row=(lane>>4)*4+j  [m89/m91]
    #pragma unroll
    for (int rs = 0; rs < 2; ++rs)
        #pragma unroll
        for (int j = 0; j < 4; ++j) {
            int row = bm + wave * 32 + rs * 16 + lq * 4 + j;
            if (row >= M) continue;
            float sl = 0.f, sr = 0.f;
            #pragma unroll
            for (int cs = 0; cs < 4; ++cs) {
                float raw = acc[rs][cs][j];
                float v = raw;
                int col = bn + cs * 16 + lr;
                if (bias) v += bias[col];
                if (relu_out) v = fmaxf(v, 0.f);
                if (Cbf) Cbf[(size_t)row * N + col] = f2bf(v);
                else     Cf [(size_t)row * N + col] = v;
                if (al) {
                    sl = fmaf(raw, alv[cs], sl);
                    sr = fmaf(raw, arv[cs], sr);
                }
            }
            if (al) {
                #pragma unroll
                for (int off = 1; off < 16; off <<= 1) {
                    sl += __shfl_xor(sl, off);
                    sr += __shfl_xor(sr, off);
                }
                if (lr == 0) {
                    el[row * HH + h_blk] = sl;
                    er[row * HH + h_blk] = sr;
                }
            }
        }
}

// ---------------------------------------------------------------------------
// CSR build: histogram -> 3-phase parallel scan -> scatter
// ---------------------------------------------------------------------------
__global__ void hist_kernel(const int* __restrict__ dst, int* __restrict__ cnt) {
    for (int i = blockIdx.x * blockDim.x + threadIdx.x; i < EE;
         i += gridDim.x * blockDim.x)
        atomicAdd(&cnt[dst[i]], 1);
}

// phase A: block b sums cnt[b*256 .. b*256+255] -> bsum[b]
__global__ __launch_bounds__(256) void scan_partial_kernel(
    const int* __restrict__ cnt, int* __restrict__ bsum) {
    __shared__ int s[256];
    int b = blockIdx.x, t = threadIdx.x;
    int i = b * 256 + t;
    s[t] = (i < NN) ? cnt[i] : 0;
    __syncthreads();
    for (int off = 128; off; off >>= 1) {
        if (t < off) s[t] += s[t + off];
        __syncthreads();
    }
    if (t == 0) bsum[b] = s[0];
}

// phase B: one block exclusive-scans bsum[SCAN_NB] -> boff
__global__ __launch_bounds__(256) void scan_bsums_kernel(
    const int* __restrict__ bsum, int* __restrict__ boff) {
    __shared__ int s[256];
    int t = threadIdx.x;
    int v = (t < SCAN_NB) ? bsum[t] : 0;
    s[t] = v;
    __syncthreads();
    #pragma unroll
    for (int off = 1; off < 256; off <<= 1) {
        int u = (t >= off) ? s[t - off] : 0;
        __syncthreads();
        s[t] += u;
        __syncthreads();
    }
    if (t < SCAN_NB) boff[t] = s[t] - v;   // exclusive
}

// phase C: block b scans its 256 counts, adds boff[b], writes rowptr (+total)
__global__ __launch_bounds__(256) void scan_final_kernel(
    const int* __restrict__ cnt, const int* __restrict__ boff,
    int* __restrict__ rowptr) {
    __shared__ int s[256];
    int b = blockIdx.x, t = threadIdx.x;
    int i = b * 256 + t;
    int v = (i < NN) ? cnt[i] : 0;
    s[t] = v;
    __syncthreads();
    #pragma unroll
    for (int off = 1; off < 256; off <<= 1) {
        int u = (t >= off) ? s[t - off] : 0;
        __syncthreads();
        s[t] += u;
        __syncthreads();
    }
    int incl = s[t] + boff[b];
    if (i < NN) rowptr[i] = incl - v;      // exclusive
    if (i == NN - 1) rowptr[NN] = incl;    // total = EE
}

__global__ void scatter_kernel(const int* __restrict__ src,
                               const int* __restrict__ dst,
                               const int* __restrict__ rowptr,
                               int* __restrict__ fill,
                               int* __restrict__ colsrc) {
    for (int i = blockIdx.x * blockDim.x + threadIdx.x; i < EE;
         i += gridDim.x * blockDim.x) {
        int d = dst[i];
        int pos = atomicAdd(&fill[d], 1);
        colsrc[rowptr[d] + pos] = src[i];
    }
}

// ---------------------------------------------------------------------------
// aggregate: per-dst-node edge softmax + message aggregation. One wave/node.
// ft is bf16: one ushort4 (8B) gather per lane per edge. (src,p) staged in
// per-wave LDS; serial loop: 2 broadcast LDS reads + 1 bf16x4 gather.
// unroll 8: gather addrs independent of acc chain -> deeper MLP.
// ---------------------------------------------------------------------------
__global__ __launch_bounds__(256) void aggregate_kernel(
    const ushort* __restrict__ ft, const float* __restrict__ el,
    const float* __restrict__ er, const int* __restrict__ rowptr,
    const int* __restrict__ colsrc, const float* __restrict__ bias,
    ushort* __restrict__ out, int relu_out) {
    __shared__ float4 plds[4][64];
    __shared__ int    slds[4][64];

    int v = (blockIdx.x * blockDim.x + threadIdx.x) >> 6;
    int lane = threadIdx.x & 63;
    int w = threadIdx.x >> 6;
    if (v >= NN) return;
    int base = rowptr[v];
    int deg = rowptr[v + 1] - base;

    const int h = lane >> 4;           // this lane's head
    float4 er4 = ((const float4*)er)[v];

    float z0 = 0.f, z1 = 0.f, z2 = 0.f, z3 = 0.f;
    float4 acc = {0.f, 0.f, 0.f, 0.f};
    const float* pf = (const float*)plds[w];

    for (int c = 0; c < deg; c += 64) {
        int clen = min(64, deg - c);
        if (lane < clen) {
            int s_j = colsrc[base + c + lane];
            float4 el4 = ((const float4*)el)[s_j];
            float p0 = expf(lrelu(el4.x + er4.x));
            float p1 = expf(lrelu(el4.y + er4.y));
            float p2 = expf(lrelu(el4.z + er4.z));
            float p3 = expf(lrelu(el4.w + er4.w));
            z0 += p0; z1 += p1; z2 += p2; z3 += p3;
            slds[w][lane] = s_j;
            plds[w][lane] = (float4){p0, p1, p2, p3};
        }
        // wave-internal LDS ordering; no __syncthreads needed
        #pragma unroll 8
        for (int jj = 0; jj < clen; ++jj) {
            int   s = slds[w][jj];                 // uniform broadcast
            float q = pf[jj * 4 + h];
            ushort4 f4 = ((const ushort4*)(ft + (size_t)s * HD))[lane];
            acc.x = fmaf(q, bf2f(f4.x), acc.x);
            acc.y = fmaf(q, bf2f(f4.y), acc.y);
            acc.z = fmaf(q, bf2f(f4.z), acc.z);
            acc.w = fmaf(q, bf2f(f4.w), acc.w);
        }
    }

    // reduce lane-partial z across the wave, then pick own head's z
    #pragma unroll
    for (int off = 32; off; off >>= 1) {
        z0 += __shfl_xor(z0, off);
        z1 += __shfl_xor(z1, off);
        z2 += __shfl_xor(z2, off);
        z3 += __shfl_xor(z3, off);
    }
    float zh = (h < 2) ? ((h == 0) ? z0 : z1) : ((h == 2) ? z2 : z3);
    float zi = 1.f / zh;

    float4 b4 = ((const float4*)bias)[lane];
    float o0 = acc.x * zi + b4.x;
    float o1 = acc.y * zi + b4.y;
    float o2 = acc.z * zi + b4.z;
    float o3 = acc.w * zi + b4.w;
    if (relu_out) {
        o0 = fmaxf(o0, 0.f); o1 = fmaxf(o1, 0.f);
        o2 = fmaxf(o2, 0.f); o3 = fmaxf(o3, 0.f);
    }
    ushort4 st = {f2bf(o0), f2bf(o1), f2bf(o2), f2bf(o3)};
    *(ushort4*)(out + (size_t)v * HD + lane * 4) = st;
}

// ---------------------------------------------------------------------------
// final: out[n] = hidden[n,:512] . Wd2 + bd2 + 0.5  (no atomics)
// ---------------------------------------------------------------------------
__global__ __launch_bounds__(256) void final_kernel(
    const float* __restrict__ hidden, const float* __restrict__ Wd2,
    const float* __restrict__ bd2, float* __restrict__ out) {
    int n = (blockIdx.x * blockDim.x + threadIdx.x) >> 6;
    int lane = threadIdx.x & 63;
    if (n >= NN) return;
    const float4* hr = (const float4*)(hidden + (size_t)n * 512);
    const float4* w  = (const float4*)Wd2;
    float4 a0 = hr[lane];
    float4 a1 = hr[lane + 64];
    float4 w0 = w[lane];
    float4 w1 = w[lane + 64];
    float s = a0.x * w0.x + a0.y * w0.y + a0.z * w0.z + a0.w * w0.w
            + a1.x * w1.x + a1.y * w1.y + a1.z * w1.z + a1.w * w1.w;
    #pragma unroll
    for (int off = 32; off; off >>= 1) s += __shfl_xor(s, off);
    if (lane == 0) out[n] = s + bd2[0] + 0.5f;
}

// ---------------------------------------------------------------------------
// pool: one block per graph; masked block reduction over all nodes (no atomics)
// ---------------------------------------------------------------------------
__global__ __launch_bounds__(256) void pool_kernel(
    const float* __restrict__ out, const int* __restrict__ graph_id,
    float* __restrict__ gout) {
    int g = blockIdx.x;
    int t = threadIdx.x;
    float s = 0.f;
    float c = 0.f;
    for (int n = t; n < NN; n += 256) {
        if (graph_id[n] == g) { s += out[n]; c += 1.f; }
    }
    __shared__ float ss[256], cc[256];
    ss[t] = s; cc[t] = c;
    __syncthreads();
    for (int off = 128; off; off >>= 1) {
        if (t < off) { ss[t] += ss[t + off]; cc[t] += cc[t + off]; }
        __syncthreads();
    }
    if (t == 0) gout[g] = ss[0] / cc[0];
}

// ---------------------------------------------------------------------------
// launch
// ---------------------------------------------------------------------------
static inline size_t align_up(size_t x, size_t a) { return (x + a - 1) & ~(a - 1); }

extern "C" void kernel_launch(void* const* d_in, const int* in_sizes, int n_in,
                              void* d_out, int out_size, void* d_ws, size_t ws_size,
                              hipStream_t stream) {
    const int*   seq    = (const int*)d_in[0];
    const float* node_s = (const float*)d_in[1];
    const int*   src    = (const int*)d_in[2];
    const int*   dst    = (const int*)d_in[3];
    const int*   graph_id = (const int*)d_in[4];
    const float* W_emb  = (const float*)d_in[5];
    const float* W0     = (const float*)d_in[6];
    const float* al0    = (const float*)d_in[7];
    const float* ar0    = (const float*)d_in[8];
    const float* b0     = (const float*)d_in[9];
    const float* W1     = (const float*)d_in[10];
    const float* al1    = (const float*)d_in[11];
    const float* ar1    = (const float*)d_in[12];
    const float* b1     = (const float*)d_in[13];
    const float* W2     = (const float*)d_in[14];
    const float* al2    = (const float*)d_in[15];
    const float* ar2    = (const float*)d_in[16];
    const float* b2     = (const float*)d_in[17];
    const float* Wd1    = (const float*)d_in[18];
    const float* bd1    = (const float*)d_in[19];
    const float* Wd2    = (const float*)d_in[20];
    const float* bd2    = (const float*)d_in[21];

    float* out_nodes  = (float*)d_out;          // [N]
    float* out_graphs = (float*)d_out + NN;     // [G]

    // workspace carve-up
    char* p = (char*)d_ws;
    size_t off = 0;
    auto alloc = [&](size_t bytes) {
        void* r = p + off;
        off = align_up(off + bytes, 256);
        return r;
    };
    ushort* ftbf  = (ushort*)alloc((size_t)NN * HD * 2);   // ft bf16 [N,256]
    float*  hidden= (float*)alloc((size_t)NN * 512 * 4);   // head GEMM out fp32
    ushort* hbf0  = (ushort*)alloc((size_t)NN * 32 * 2);   // embed output bf16 [N,32]
    ushort* hbuf  = (ushort*)alloc((size_t)NN * HD * 2);   // h between layers, bf16
    float*  el    = (float*)alloc((size_t)NN * HH * 4);
    float*  er    = (float*)alloc((size_t)NN * HH * 4);
    int*    rowptr= (int*)alloc((size_t)(NN + 1) * 4);
    int*    fill  = (int*)alloc((size_t)NN * 4);
    int*    colsrc= (int*)alloc((size_t)EE * 4);
    int*    bsum  = (int*)alloc(256 * 4);
    int*    boff  = (int*)alloc(256 * 4);
    ushort* Wt0   = (ushort*)alloc((size_t)HD * 32 * 2);   // [256][32]
    ushort* Wt1   = (ushort*)alloc((size_t)HD * HD * 2);   // [256][256]
    ushort* Wt2   = (ushort*)alloc((size_t)HD * HD * 2);
    ushort* Wtd1  = (ushort*)alloc((size_t)512 * HD * 2);  // [512][256]
    (void)ws_size;

    // ---- CSR build (dst-grouped), 3-phase parallel scan ----
    hipMemsetAsync(fill, 0, (size_t)NN * 4, stream);
    hist_kernel<<<1024, 256, 0, stream>>>(dst, fill);
    scan_partial_kernel<<<SCAN_NB, 256, 0, stream>>>(fill, bsum);
    scan_bsums_kernel<<<1, 256, 0, stream>>>(bsum, boff);
    scan_final_kernel<<<SCAN_NB, 256, 0, stream>>>(fill, boff, rowptr);
    hipMemsetAsync(fill, 0, (size_t)NN * 4, stream);
    scatter_kernel<<<1024, 256, 0, stream>>>(src, dst, rowptr, fill, colsrc);

    // ---- weight transposes (bf16) ----
    wtrans_kernel<<<(HD * 32 + 255) / 256, 256, 0, stream>>>(W0, Wt0, NODE_IN, HD, 32);
    wtrans_kernel<<<(HD * HD + 255) / 256, 256, 0, stream>>>(W1, Wt1, HD, HD, HD);
    wtrans_kernel<<<(HD * HD + 255) / 256, 256, 0, stream>>>(W2, Wt2, HD, HD, HD);
    wtrans_kernel<<<(512 * HD + 255) / 256, 256, 0, stream>>>(Wd1, Wtd1, HD, 512, HD);

    // ---- embedding (bf16, padded to K=32) ----
    embed_bf16_kernel<<<(NN * 32 + 255) / 256, 256, 0, stream>>>(seq, node_s, W_emb, hbf0);

    const int nodeWaves = (NN * 64 + 255) / 256;  // blocks of 4 waves
    dim3 gemm256(256 / 64, (NN + 127) / 128);
    dim3 gemm512(512 / 64, (NN + 127) / 128);

    // ---- layer 0 (scores fused into GEMM epilogue) ----
    gemm_mfma_kernel<<<gemm256, 256, 0, stream>>>(hbf0, Wt0, ftbf, nullptr, nullptr,
                                                  al0, ar0, el, er, NN, HD, 32, 0);
    aggregate_kernel<<<nodeWaves, 256, 0, stream>>>(ftbf, el, er, rowptr, colsrc, b0, hbuf, 0);

    // ---- layer 1 ----
    gemm_mfma_kernel<<<gemm256, 256, 0, stream>>>(hbuf, Wt1, ftbf, nullptr, nullptr,
                                                  al1, ar1, el, er, NN, HD, HD, 0);
    aggregate_kernel<<<nodeWaves, 256, 0, stream>>>(ftbf, el, er, rowptr, colsrc, b1, hbuf, 0);

    // ---- layer 2 (relu fused into aggregate epilogue) ----
    gemm_mfma_kernel<<<gemm256, 256, 0, stream>>>(hbuf, Wt2, ftbf, nullptr, nullptr,
                                                  al2, ar2, el, er, NN, HD, HD, 0);
    aggregate_kernel<<<nodeWaves, 256, 0, stream>>>(ftbf, el, er, rowptr, colsrc, b2, hbuf, 1);

    // ---- dense head: hidden = relu(h @ Wd1 + bd1)  (fp32 out, no scores) ----
    gemm_mfma_kernel<<<gemm512, 256, 0, stream>>>(hbuf, Wtd1, nullptr, hidden, bd1,
                                                  nullptr, nullptr, nullptr, nullptr,
                                                  NN, 512, HD, 1);
    final_kernel<<<nodeWaves, 256, 0, stream>>>(hidden, Wd2, bd2, out_nodes);
    pool_kernel<<<GG, 256, 0, stream>>>(out_nodes, graph_id, out_graphs);
}

// Round 16
// 558.230 us; speedup vs baseline: 1.5140x; 1.1411x over previous
//
#include <hip/hip_runtime.h>
#include <hip/hip_bf16.h>
#include <float.h>

#define NN 50000
#define EE 800000
#define GG 50
#define HH 4
#define DD 64
#define HD 256
#define NODE_IN 26
#define NEG_SLOPE 0.2f
#define SCAN_NB ((NN + 255) / 256)   // 196
#define PB 128                        // pool partial blocks

typedef __attribute__((ext_vector_type(8))) short short8v;   // 8 bf16 = 4 VGPR
typedef __attribute__((ext_vector_type(4))) float floatx4;   // MFMA C/D

static __device__ __forceinline__ ushort f2bf(float f) {
    __hip_bfloat16 b = __float2bfloat16(f);
    return *(ushort*)&b;
}

static __device__ __forceinline__ float bf2f(ushort u) {
    return __uint_as_float(((unsigned)u) << 16);
}

static __device__ __forceinline__ float lrelu(float e) {
    return (e >= 0.f) ? e : NEG_SLOPE * e;
}

// ---------------------------------------------------------------------------
// embed -> bf16 padded: hbf[n][j], j in [0,32): W_emb | node_s | 0-pad
// ---------------------------------------------------------------------------
__global__ void embed_bf16_kernel(const int* __restrict__ seq,
                                  const float* __restrict__ node_s,
                                  const float* __restrict__ W_emb,
                                  ushort* __restrict__ hbf) {
    int idx = blockIdx.x * blockDim.x + threadIdx.x;
    if (idx >= NN * 32) return;
    int n = idx >> 5;
    int j = idx & 31;
    float v = 0.f;
    if (j < 20)      v = W_emb[seq[n] * 20 + j];
    else if (j < 26) v = node_s[n * 6 + (j - 20)];
    hbf[idx] = f2bf(v);
}

// ---------------------------------------------------------------------------
// weight transpose+convert: W fp32 [K,N] -> Wt bf16 [N,Kp] (zero-pad k>=K)
// ---------------------------------------------------------------------------
__global__ void wtrans_kernel(const float* __restrict__ W,
                              ushort* __restrict__ Wt,
                              int K, int N, int Kp) {
    int idx = blockIdx.x * blockDim.x + threadIdx.x;
    if (idx >= N * Kp) return;
    int n = idx / Kp;
    int k = idx - n * Kp;
    float v = (k < K) ? W[(size_t)k * N + n] : 0.f;
    Wt[idx] = f2bf(v);
}

// ---------------------------------------------------------------------------
// MFMA bf16 GEMM: C = A[M,Kp] @ Bt[N,Kp]^T   (+bias, optional relu)
// Output: bf16 (Cbf) or fp32 (Cf).
// Fused GAT scores (when al!=nullptr): each 64-col block == one head.
// block: 256 thr = 4 waves; tile 128(M) x 64(N); K-step 32.
// ---------------------------------------------------------------------------
__global__ __launch_bounds__(256) void gemm_mfma_kernel(
    const ushort* __restrict__ A, const ushort* __restrict__ Bt,
    ushort* __restrict__ Cbf, float* __restrict__ Cf,
    const float* __restrict__ bias,
    const float* __restrict__ al, const float* __restrict__ ar,
    float* __restrict__ el, float* __restrict__ er,
    int M, int N, int Kp, int relu_out) {
    __shared__ ushort As[128][40];
    __shared__ ushort Bs[64][40];

    int tid  = threadIdx.x;
    int wave = tid >> 6;
    int lane = tid & 63;
    int bm = blockIdx.y * 128;
    int bn = blockIdx.x * 64;

    floatx4 acc[2][4];
    #pragma unroll
    for (int i = 0; i < 2; ++i)
        #pragma unroll
        for (int j = 0; j < 4; ++j)
            acc[i][j] = (floatx4){0.f, 0.f, 0.f, 0.f};

    const int lr = lane & 15;          // row/col within 16-subtile
    const int lk = (lane >> 4) * 8;    // k-offset of this lane's 8 elements
    const int lq = lane >> 4;          // C row group

    for (int k0 = 0; k0 < Kp; k0 += 32) {
        #pragma unroll
        for (int p = 0; p < 2; ++p) {
            int idx = p * 256 + tid;
            int r = idx >> 2, kk = (idx & 3) * 8;
            int gr = bm + r;
            short8v v = {};
            if (gr < M) v = *(const short8v*)(A + (size_t)gr * Kp + k0 + kk);
            *(short8v*)(&As[r][kk]) = v;
        }
        {
            int c = tid >> 2, kk = (tid & 3) * 8;
            short8v v = *(const short8v*)(Bt + (size_t)(bn + c) * Kp + k0 + kk);
            *(short8v*)(&Bs[c][kk]) = v;
        }
        __syncthreads();

        short8v bfrag[4];
        #pragma unroll
        for (int cs = 0; cs < 4; ++cs)
            bfrag[cs] = *(const short8v*)(&Bs[cs * 16 + lr][lk]);
        #pragma unroll
        for (int rs = 0; rs < 2; ++rs) {
            short8v afrag = *(const short8v*)(&As[wave * 32 + rs * 16 + lr][lk]);
            #pragma unroll
            for (int cs = 0; cs < 4; ++cs)
                acc[rs][cs] = __builtin_amdgcn_mfma_f32_16x16x32_bf16(
                    afrag, bfrag[cs], acc[rs][cs], 0, 0, 0);
        }
        __syncthreads();
    }

    // fused-score weight slices for this head block (bn/64 == head)
    const int h_blk = bn >> 6;
    float alv[4], arv[4];
    if (al) {
        #pragma unroll
        for (int cs = 0; cs < 4; ++cs) {
            alv[cs] = al[h_blk * DD + cs * 16 + lr];
            arv[cs] = ar[h_blk * DD + cs * 16 + lr];
        }
    }

    // epilogue: C/D layout col=lane&15, row=(lane>>4)*4+j  [m89/m91]
    #pragma unroll
    for (int rs = 0; rs < 2; ++rs)
        #pragma unroll
        for (int j = 0; j < 4; ++j) {
            int row = bm + wave * 32 + rs * 16 + lq * 4 + j;
            if (row >= M) continue;
            float sl = 0.f, sr = 0.f;
            #pragma unroll
            for (int cs = 0; cs < 4; ++cs) {
                float raw = acc[rs][cs][j];
                float v = raw;
                int col = bn + cs * 16 + lr;
                if (bias) v += bias[col];
                if (relu_out) v = fmaxf(v, 0.f);
                if (Cbf) Cbf[(size_t)row * N + col] = f2bf(v);
                else     Cf [(size_t)row * N + col] = v;
                if (al) {
                    sl = fmaf(raw, alv[cs], sl);
                    sr = fmaf(raw, arv[cs], sr);
                }
            }
            if (al) {
                #pragma unroll
                for (int off = 1; off < 16; off <<= 1) {
                    sl += __shfl_xor(sl, off);
                    sr += __shfl_xor(sr, off);
                }
                if (lr == 0) {
                    el[row * HH + h_blk] = sl;
                    er[row * HH + h_blk] = sr;
                }
            }
        }
}

// ---------------------------------------------------------------------------
// CSR build: histogram -> 3-phase parallel scan -> scatter
// ---------------------------------------------------------------------------
__global__ void hist_kernel(const int* __restrict__ dst, int* __restrict__ cnt) {
    for (int i = blockIdx.x * blockDim.x + threadIdx.x; i < EE;
         i += gridDim.x * blockDim.x)
        atomicAdd(&cnt[dst[i]], 1);
}

// phase A: block b sums cnt[b*256 .. b*256+255] -> bsum[b]
__global__ __launch_bounds__(256) void scan_partial_kernel(
    const int* __restrict__ cnt, int* __restrict__ bsum) {
    __shared__ int s[256];
    int b = blockIdx.x, t = threadIdx.x;
    int i = b * 256 + t;
    s[t] = (i < NN) ? cnt[i] : 0;
    __syncthreads();
    for (int off = 128; off; off >>= 1) {
        if (t < off) s[t] += s[t + off];
        __syncthreads();
    }
    if (t == 0) bsum[b] = s[0];
}

// phase B: one block exclusive-scans bsum[SCAN_NB] -> boff
__global__ __launch_bounds__(256) void scan_bsums_kernel(
    const int* __restrict__ bsum, int* __restrict__ boff) {
    __shared__ int s[256];
    int t = threadIdx.x;
    int v = (t < SCAN_NB) ? bsum[t] : 0;
    s[t] = v;
    __syncthreads();
    #pragma unroll
    for (int off = 1; off < 256; off <<= 1) {
        int u = (t >= off) ? s[t - off] : 0;
        __syncthreads();
        s[t] += u;
        __syncthreads();
    }
    if (t < SCAN_NB) boff[t] = s[t] - v;   // exclusive
}

// phase C: block b scans its 256 counts, adds boff[b], writes rowptr (+total)
__global__ __launch_bounds__(256) void scan_final_kernel(
    const int* __restrict__ cnt, const int* __restrict__ boff,
    int* __restrict__ rowptr) {
    __shared__ int s[256];
    int b = blockIdx.x, t = threadIdx.x;
    int i = b * 256 + t;
    int v = (i < NN) ? cnt[i] : 0;
    s[t] = v;
    __syncthreads();
    #pragma unroll
    for (int off = 1; off < 256; off <<= 1) {
        int u = (t >= off) ? s[t - off] : 0;
        __syncthreads();
        s[t] += u;
        __syncthreads();
    }
    int incl = s[t] + boff[b];
    if (i < NN) rowptr[i] = incl - v;      // exclusive
    if (i == NN - 1) rowptr[NN] = incl;    // total = EE
}

__global__ void scatter_kernel(const int* __restrict__ src,
                               const int* __restrict__ dst,
                               const int* __restrict__ rowptr,
                               int* __restrict__ fill,
                               int* __restrict__ colsrc) {
    for (int i = blockIdx.x * blockDim.x + threadIdx.x; i < EE;
         i += gridDim.x * blockDim.x) {
        int d = dst[i];
        int pos = atomicAdd(&fill[d], 1);
        colsrc[rowptr[d] + pos] = src[i];
    }
}

// ---------------------------------------------------------------------------
// aggregate: per-dst-node edge softmax + message aggregation. One wave/node.
// ft is bf16: one ushort4 (8B) gather per lane per edge. (src,p) staged in
// per-wave LDS; serial loop: 2 broadcast LDS reads + 1 bf16x4 gather.
// ---------------------------------------------------------------------------
__global__ __launch_bounds__(256) void aggregate_kernel(
    const ushort* __restrict__ ft, const float* __restrict__ el,
    const float* __restrict__ er, const int* __restrict__ rowptr,
    const int* __restrict__ colsrc, const float* __restrict__ bias,
    ushort* __restrict__ out, int relu_out) {
    __shared__ float4 plds[4][64];
    __shared__ int    slds[4][64];

    int v = (blockIdx.x * blockDim.x + threadIdx.x) >> 6;
    int lane = threadIdx.x & 63;
    int w = threadIdx.x >> 6;
    if (v >= NN) return;
    int base = rowptr[v];
    int deg = rowptr[v + 1] - base;

    const int h = lane >> 4;           // this lane's head
    float4 er4 = ((const float4*)er)[v];

    float z0 = 0.f, z1 = 0.f, z2 = 0.f, z3 = 0.f;
    float4 acc = {0.f, 0.f, 0.f, 0.f};
    const float* pf = (const float*)plds[w];

    for (int c = 0; c < deg; c += 64) {
        int clen = min(64, deg - c);
        if (lane < clen) {
            int s_j = colsrc[base + c + lane];
            float4 el4 = ((const float4*)el)[s_j];
            float p0 = expf(lrelu(el4.x + er4.x));
            float p1 = expf(lrelu(el4.y + er4.y));
            float p2 = expf(lrelu(el4.z + er4.z));
            float p3 = expf(lrelu(el4.w + er4.w));
            z0 += p0; z1 += p1; z2 += p2; z3 += p3;
            slds[w][lane] = s_j;
            plds[w][lane] = (float4){p0, p1, p2, p3};
        }
        // wave-internal LDS ordering; no __syncthreads needed
        #pragma unroll 8
        for (int jj = 0; jj < clen; ++jj) {
            int   s = slds[w][jj];                 // uniform broadcast
            float q = pf[jj * 4 + h];
            ushort4 f4 = ((const ushort4*)(ft + (size_t)s * HD))[lane];
            acc.x = fmaf(q, bf2f(f4.x), acc.x);
            acc.y = fmaf(q, bf2f(f4.y), acc.y);
            acc.z = fmaf(q, bf2f(f4.z), acc.z);
            acc.w = fmaf(q, bf2f(f4.w), acc.w);
        }
    }

    // reduce lane-partial z across the wave, then pick own head's z
    #pragma unroll
    for (int off = 32; off; off >>= 1) {
        z0 += __shfl_xor(z0, off);
        z1 += __shfl_xor(z1, off);
        z2 += __shfl_xor(z2, off);
        z3 += __shfl_xor(z3, off);
    }
    float zh = (h < 2) ? ((h == 0) ? z0 : z1) : ((h == 2) ? z2 : z3);
    float zi = 1.f / zh;

    float4 b4 = ((const float4*)bias)[lane];
    float o0 = acc.x * zi + b4.x;
    float o1 = acc.y * zi + b4.y;
    float o2 = acc.z * zi + b4.z;
    float o3 = acc.w * zi + b4.w;
    if (relu_out) {
        o0 = fmaxf(o0, 0.f); o1 = fmaxf(o1, 0.f);
        o2 = fmaxf(o2, 0.f); o3 = fmaxf(o3, 0.f);
    }
    ushort4 st = {f2bf(o0), f2bf(o1), f2bf(o2), f2bf(o3)};
    *(ushort4*)(out + (size_t)v * HD + lane * 4) = st;
}

// ---------------------------------------------------------------------------
// final: out[n] = hidden[n,:512] . Wd2 + bd2 + 0.5  (no atomics)
// ---------------------------------------------------------------------------
__global__ __launch_bounds__(256) void final_kernel(
    const float* __restrict__ hidden, const float* __restrict__ Wd2,
    const float* __restrict__ bd2, float* __restrict__ out) {
    int n = (blockIdx.x * blockDim.x + threadIdx.x) >> 6;
    int lane = threadIdx.x & 63;
    if (n >= NN) return;
    const float4* hr = (const float4*)(hidden + (size_t)n * 512);
    const float4* w  = (const float4*)Wd2;
    float4 a0 = hr[lane];
    float4 a1 = hr[lane + 64];
    float4 w0 = w[lane];
    float4 w1 = w[lane + 64];
    float s = a0.x * w0.x + a0.y * w0.y + a0.z * w0.z + a0.w * w0.w
            + a1.x * w1.x + a1.y * w1.y + a1.z * w1.z + a1.w * w1.w;
    #pragma unroll
    for (int off = 32; off; off >>= 1) s += __shfl_xor(s, off);
    if (lane == 0) out[n] = s + bd2[0] + 0.5f;
}

// ---------------------------------------------------------------------------
// pool phase 1: PB blocks grid-stride nodes; LDS-accumulate per-graph
// partial sums; write psum[g][b], pcnt[g][b].  No global atomics.
// ---------------------------------------------------------------------------
__global__ __launch_bounds__(256) void pool_partial_kernel(
    const float* __restrict__ out, const int* __restrict__ graph_id,
    float* __restrict__ psum, float* __restrict__ pcnt) {
    __shared__ float ls[64], lc[64];
    int b = blockIdx.x, t = threadIdx.x;
    if (t < 64) { ls[t] = 0.f; lc[t] = 0.f; }
    __syncthreads();
    for (int n = b * 256 + t; n < NN; n += PB * 256) {
        int g = graph_id[n];
        atomicAdd(&ls[g], out[n]);
        atomicAdd(&lc[g], 1.f);
    }
    __syncthreads();
    if (t < GG) {
        psum[t * PB + b] = ls[t];
        pcnt[t * PB + b] = lc[t];
    }
}

// ---------------------------------------------------------------------------
// pool phase 2: one wave per graph; reduce PB partials; gout = sum/cnt
// ---------------------------------------------------------------------------
__global__ __launch_bounds__(256) void pool_final_kernel(
    const float* __restrict__ psum, const float* __restrict__ pcnt,
    float* __restrict__ gout) {
    int g = (blockIdx.x * blockDim.x + threadIdx.x) >> 6;
    int lane = threadIdx.x & 63;
    if (g >= GG) return;
    float s = psum[g * PB + lane] + psum[g * PB + 64 + lane];
    float c = pcnt[g * PB + lane] + pcnt[g * PB + 64 + lane];
    #pragma unroll
    for (int off = 32; off; off >>= 1) {
        s += __shfl_xor(s, off);
        c += __shfl_xor(c, off);
    }
    if (lane == 0) gout[g] = s / c;
}

// ---------------------------------------------------------------------------
// launch
// ---------------------------------------------------------------------------
static inline size_t align_up(size_t x, size_t a) { return (x + a - 1) & ~(a - 1); }

extern "C" void kernel_launch(void* const* d_in, const int* in_sizes, int n_in,
                              void* d_out, int out_size, void* d_ws, size_t ws_size,
                              hipStream_t stream) {
    const int*   seq    = (const int*)d_in[0];
    const float* node_s = (const float*)d_in[1];
    const int*   src    = (const int*)d_in[2];
    const int*   dst    = (const int*)d_in[3];
    const int*   graph_id = (const int*)d_in[4];
    const float* W_emb  = (const float*)d_in[5];
    const float* W0     = (const float*)d_in[6];
    const float* al0    = (const float*)d_in[7];
    const float* ar0    = (const float*)d_in[8];
    const float* b0     = (const float*)d_in[9];
    const float* W1     = (const float*)d_in[10];
    const float* al1    = (const float*)d_in[11];
    const float* ar1    = (const float*)d_in[12];
    const float* b1     = (const float*)d_in[13];
    const float* W2     = (const float*)d_in[14];
    const float* al2    = (const float*)d_in[15];
    const float* ar2    = (const float*)d_in[16];
    const float* b2     = (const float*)d_in[17];
    const float* Wd1    = (const float*)d_in[18];
    const float* bd1    = (const float*)d_in[19];
    const float* Wd2    = (const float*)d_in[20];
    const float* bd2    = (const float*)d_in[21];

    float* out_nodes  = (float*)d_out;          // [N]
    float* out_graphs = (float*)d_out + NN;     // [G]

    // workspace carve-up
    char* p = (char*)d_ws;
    size_t off = 0;
    auto alloc = [&](size_t bytes) {
        void* r = p + off;
        off = align_up(off + bytes, 256);
        return r;
    };
    ushort* ftbf  = (ushort*)alloc((size_t)NN * HD * 2);   // ft bf16 [N,256]
    float*  hidden= (float*)alloc((size_t)NN * 512 * 4);   // head GEMM out fp32
    ushort* hbf0  = (ushort*)alloc((size_t)NN * 32 * 2);   // embed output bf16 [N,32]
    ushort* hbuf  = (ushort*)alloc((size_t)NN * HD * 2);   // h between layers, bf16
    float*  el    = (float*)alloc((size_t)NN * HH * 4);
    float*  er    = (float*)alloc((size_t)NN * HH * 4);
    int*    rowptr= (int*)alloc((size_t)(NN + 1) * 4);
    int*    fill  = (int*)alloc((size_t)NN * 4);
    int*    colsrc= (int*)alloc((size_t)EE * 4);
    int*    bsum  = (int*)alloc(256 * 4);
    int*    boff  = (int*)alloc(256 * 4);
    float*  psum  = (float*)alloc((size_t)64 * PB * 4);
    float*  pcnt  = (float*)alloc((size_t)64 * PB * 4);
    ushort* Wt0   = (ushort*)alloc((size_t)HD * 32 * 2);   // [256][32]
    ushort* Wt1   = (ushort*)alloc((size_t)HD * HD * 2);   // [256][256]
    ushort* Wt2   = (ushort*)alloc((size_t)HD * HD * 2);
    ushort* Wtd1  = (ushort*)alloc((size_t)512 * HD * 2);  // [512][256]
    (void)ws_size;

    // ---- CSR build (dst-grouped), 3-phase parallel scan ----
    hipMemsetAsync(fill, 0, (size_t)NN * 4, stream);
    hist_kernel<<<1024, 256, 0, stream>>>(dst, fill);
    scan_partial_kernel<<<SCAN_NB, 256, 0, stream>>>(fill, bsum);
    scan_bsums_kernel<<<1, 256, 0, stream>>>(bsum, boff);
    scan_final_kernel<<<SCAN_NB, 256, 0, stream>>>(fill, boff, rowptr);
    hipMemsetAsync(fill, 0, (size_t)NN * 4, stream);
    scatter_kernel<<<1024, 256, 0, stream>>>(src, dst, rowptr, fill, colsrc);

    // ---- weight transposes (bf16) ----
    wtrans_kernel<<<(HD * 32 + 255) / 256, 256, 0, stream>>>(W0, Wt0, NODE_IN, HD, 32);
    wtrans_kernel<<<(HD * HD + 255) / 256, 256, 0, stream>>>(W1, Wt1, HD, HD, HD);
    wtrans_kernel<<<(HD * HD + 255) / 256, 256, 0, stream>>>(W2, Wt2, HD, HD, HD);
    wtrans_kernel<<<(512 * HD + 255) / 256, 256, 0, stream>>>(Wd1, Wtd1, HD, 512, HD);

    // ---- embedding (bf16, padded to K=32) ----
    embed_bf16_kernel<<<(NN * 32 + 255) / 256, 256, 0, stream>>>(seq, node_s, W_emb, hbf0);

    const int nodeWaves = (NN * 64 + 255) / 256;  // blocks of 4 waves
    dim3 gemm256(256 / 64, (NN + 127) / 128);
    dim3 gemm512(512 / 64, (NN + 127) / 128);

    // ---- layer 0 (scores fused into GEMM epilogue) ----
    gemm_mfma_kernel<<<gemm256, 256, 0, stream>>>(hbf0, Wt0, ftbf, nullptr, nullptr,
                                                  al0, ar0, el, er, NN, HD, 32, 0);
    aggregate_kernel<<<nodeWaves, 256, 0, stream>>>(ftbf, el, er, rowptr, colsrc, b0, hbuf, 0);

    // ---- layer 1 ----
    gemm_mfma_kernel<<<gemm256, 256, 0, stream>>>(hbuf, Wt1, ftbf, nullptr, nullptr,
                                                  al1, ar1, el, er, NN, HD, HD, 0);
    aggregate_kernel<<<nodeWaves, 256, 0, stream>>>(ftbf, el, er, rowptr, colsrc, b1, hbuf, 0);

    // ---- layer 2 (relu fused into aggregate epilogue) ----
    gemm_mfma_kernel<<<gemm256, 256, 0, stream>>>(hbuf, Wt2, ftbf, nullptr, nullptr,
                                                  al2, ar2, el, er, NN, HD, HD, 0);
    aggregate_kernel<<<nodeWaves, 256, 0, stream>>>(ftbf, el, er, rowptr, colsrc, b2, hbuf, 1);

    // ---- dense head: hidden = relu(h @ Wd1 + bd1)  (fp32 out, no scores) ----
    gemm_mfma_kernel<<<gemm512, 256, 0, stream>>>(hbuf, Wtd1, nullptr, hidden, bd1,
                                                  nullptr, nullptr, nullptr, nullptr,
                                                  NN, 512, HD, 1);
    final_kernel<<<nodeWaves, 256, 0, stream>>>(hidden, Wd2, bd2, out_nodes);
    pool_partial_kernel<<<PB, 256, 0, stream>>>(out_nodes, graph_id, psum, pcnt);
    pool_final_kernel<<<(GG * 64 + 255) / 256, 256, 0, stream>>>(psum, pcnt, out_graphs);
}